// Round 32
// baseline (112.787 us; speedup 1.0000x reference)
//
#include <hip/hip_runtime.h>

#define NA 5
#define LL 500
#define DD 300
#define H1 10
#define H2 50
#define NB 256
#define VV 50000
#define PSTR 56   // projT row stride (floats): 16B-aligned rows
#define ADS 11    // adoc LDS row stride (odd -> conflict-free)

// r32: k_vproj (aspect, h-half)-per-wave. Empirical law r26-r31: k_vproj
// runtime tracks TOTAL WAVES (782w->85us, 1955w->82, 3910w->68) — it is
// latency-bound; wave count is the only lever that moves it. This round:
// 640-thr blocks = 10 waves (wa = wv>>1, hh = wv&1), 5 channels/wave,
// grid 782 -> 7820 waves ~30/CU (3-block/CU thread cap, LDS 15.2KBx3
// fits). Staging REMAPS each 40-float (a,db) slice into two contiguous
// 20-float halves [hh][dd*5+h'] (r19-proven value permutation) so reads
// stay aligned b128 with literal bases. Per-channel d-chains textually
// unchanged -> bitwise (absmax-0.0 lineage). acc[5]+prefetch ~30 VGPR.
// WRITE_SIZE spill tripwire: must stay ~10.9 MB.

__global__ __launch_bounds__(640, 1)
void k_vproj(const float* __restrict__ Wemb,
             const float* __restrict__ AP,   // [A][D][H1]
             float* __restrict__ projT)      // [VV][PSTR]
{
    extern __shared__ char smem[];
    float* apS = (float*)smem;               // 3800 f = 15200 B (remapped)

    const int tid  = threadIdx.x;
    const int wv   = tid >> 6;               // 0..9
    const int wa   = wv >> 1;                // aspect (uniform/wave)
    const int hh   = wv & 1;                 // h-half (uniform/wave)
    const int lane = tid & 63;
    const int v    = blockIdx.x * 64 + lane;
    const bool actV = (v < VV);
    const int vc = actV ? v : (VV - 1);      // clamp: compute, don't store

    float acc[5];
    #pragma unroll
    for (int h = 0; h < 5; ++h) acc[h] = 0.f;

    const float4* e4 = (const float4*)(Wemb + (long)vc * DD);
    float4 a0 = e4[0], a1 = e4[1];

    const int db0s[5] = {0, 19, 38, 57, 75};
    #pragma unroll
    for (int p = 0; p < 4; ++p) {
        const int db0 = db0s[p], db1 = db0s[p + 1];
        const int nf4 = (db1 - db0) * 10;

        __syncthreads();
        // stage with remap: slice float q = dr*40 + dd*10 + h  ->
        //   apS[a*760 + dr*40 + (h/5)*20 + dd*5 + h%5]
        for (int i = tid; i < NA * 190; i += 640) {
            const int a_ = i / 190, j = i - a_ * 190;
            if (j < nf4) {
                const float4 vv4 = ((const float4*)(AP + a_ * (DD * H1) + db0 * 40))[j];
                #pragma unroll
                for (int k = 0; k < 4; ++k) {
                    const int q  = 4 * j + k;
                    const int dr = q / 40;
                    const int r  = q - dr * 40;
                    const int dd = r / 10, h = r - dd * 10;
                    const int cg = h / 5,  hp = h - cg * 5;
                    apS[a_ * 760 + dr * 40 + cg * 20 + dd * 5 + hp] =
                        ((const float*)&vv4)[k];
                }
            }
        }
        __syncthreads();

        for (int db = db0; db < db1; ++db) {
            float4 a2 = a1;
            if (db < 73) a2 = e4[db + 2];             // 2-deep prefetch
            const float av0 = a0.x, av1 = a0.y, av2 = a0.z, av3 = a0.w;
            const int o = (db - db0) * 40;
            #pragma unroll
            for (int a_ = 0; a_ < NA; ++a_) {
                if (a_ == wa) {   // wave-uniform guard -> exec-skip, literal base
                    #pragma unroll
                    for (int cg = 0; cg < 2; ++cg) {
                        if (cg == hh) {   // wave-uniform -> literal base
                            const float4* wp4 =
                                (const float4*)(apS + a_ * 760 + o + cg * 20);
                            float w[20];
                            #pragma unroll
                            for (int j = 0; j < 5; ++j)
                                *reinterpret_cast<float4*>(&w[4 * j]) = wp4[j];
                            #pragma unroll
                            for (int hp = 0; hp < 5; ++hp) {
                                const float w0 = w[hp],      w1 = w[5 + hp],
                                            w2 = w[10 + hp], w3 = w[15 + hp];
                                acc[hp] += av0 * w0 + av1 * w1 + av2 * w2 + av3 * w3;
                            }
                        }
                    }
                }
            }
            a0 = a1; a1 = a2;
        }
    }

    if (actV) {
        float* o = projT + (long)v * PSTR + wa * H1 + hh * 5;
        #pragma unroll
        for (int j = 0; j < 5; ++j) o[j] = acc[j];
    }
}

__global__ __launch_bounds__(256, 1)
void k_attn2(const int* __restrict__ Uids, const int* __restrict__ Iids,
             const int* __restrict__ Udocs, const int* __restrict__ Idocs,
             const float* __restrict__ projT,
             const float* __restrict__ AE,   // [A][30]
             float* __restrict__ Rep)        // [2][B][A][H1]
{
    __shared__ float adoc[LL][ADS];
    __shared__ float lg[LL];

    const int tid  = threadIdx.x;
    const int bid  = blockIdx.x;
    const int side = bid >> 8;
    const int b    = bid & 255;

    const int* ids  = side ? Iids : Uids;
    const int* docs = side ? Idocs : Udocs;
    const int uid = ids[b];
    const int* doc = docs + (long)uid * LL;

    const bool act = (tid < 250);
    float accA[NA * H1], accB[NA * H1];
    if (act) {
        const float* pA = projT + (long)doc[tid] * PSTR;
        const float* pB = projT + (long)doc[tid + 250] * PSTR;
        #pragma unroll
        for (int j = 0; j < 12; ++j) {
            *reinterpret_cast<float4*>(&accA[4 * j]) = ((const float4*)pA)[j];
            *reinterpret_cast<float4*>(&accB[4 * j]) = ((const float4*)pB)[j];
        }
        accA[48] = pA[48]; accA[49] = pA[49];
        accB[48] = pB[48]; accB[49] = pB[49];
    }

    // ---- phase 2: one aspect at a time through LDS (r16 verbatim) ----
    #pragma unroll
    for (int a_ = 0; a_ < NA; ++a_) {
        __syncthreads();
        if (act) {
            #pragma unroll
            for (int h = 0; h < H1; ++h) {
                adoc[tid][h]       = accA[a_ * H1 + h];
                adoc[tid + 250][h] = accB[a_ * H1 + h];
            }
        }
        __syncthreads();

        for (int l = tid; l < LL; l += 256) {
            const float* aerow = AE + a_ * 30;
            float s = 0.f;
            if (l > 0) {
                const float* ad = &adoc[l - 1][0];
                #pragma unroll
                for (int h = 0; h < H1; ++h) s += ad[h] * aerow[h];
            }
            {
                const float* ad = &adoc[l][0];
                #pragma unroll
                for (int h = 0; h < H1; ++h) s += ad[h] * aerow[H1 + h];
            }
            if (l < LL - 1) {
                const float* ad = &adoc[l + 1][0];
                #pragma unroll
                for (int h = 0; h < H1; ++h) s += ad[h] * aerow[2 * H1 + h];
            }
            lg[l] = s;
        }
        __syncthreads();

        if (tid < 64) {
            const int lane = tid;
            float mx = -1e30f;
            for (int p = lane; p < LL; p += 64) mx = fmaxf(mx, lg[p]);
            #pragma unroll
            for (int o = 32; o; o >>= 1) mx = fmaxf(mx, __shfl_xor(mx, o, 64));
            float sum = 0.f;
            for (int p = lane; p < LL; p += 64) {
                float pr = expf(lg[p] - mx);
                lg[p] = pr;
                sum += pr;
            }
            #pragma unroll
            for (int o = 32; o; o >>= 1) sum += __shfl_xor(sum, o, 64);
            float r[H1];
            #pragma unroll
            for (int h = 0; h < H1; ++h) r[h] = 0.f;
            for (int p = lane; p < LL; p += 64) {
                const float pr = lg[p];
                const float* ad = &adoc[p][0];
                #pragma unroll
                for (int h = 0; h < H1; ++h) r[h] += pr * ad[h];
            }
            #pragma unroll
            for (int h = 0; h < H1; ++h) {
                #pragma unroll
                for (int o = 32; o; o >>= 1) r[h] += __shfl_xor(r[h], o, 64);
            }
            if (lane == 0) {
                const float inv = 1.f / sum;
                float* out = Rep + (((long)side * NB + b) * NA + a_) * H1;
                #pragma unroll
                for (int h = 0; h < H1; ++h) out[h] = r[h] * inv;
            }
        }
    }
}

// ---------------- fallback fused path (r20, 158 us) ----------------
__global__ __launch_bounds__(256, 1)
void k_aspect(const int* __restrict__ Uids, const int* __restrict__ Iids,
              const int* __restrict__ Udocs, const int* __restrict__ Idocs,
              const float* __restrict__ Wemb,
              const float* __restrict__ AE,
              const float* __restrict__ AP,
              float* __restrict__ Rep)
{
    extern __shared__ char smem[];
    float* apS = (float*)smem;
    float (*adoc)[ADS] = (float(*)[ADS])(smem + 15200);
    float* lg = (float*)(smem + 15200 + 22000);

    const int tid  = threadIdx.x;
    const int bid  = blockIdx.x;
    const int side = bid >> 8;
    const int b    = bid & 255;

    const int* ids  = side ? Iids : Uids;
    const int* docs = side ? Idocs : Udocs;
    const int uid = ids[b];
    const int* doc = docs + (long)uid * LL;

    float accA[NA * H1], accB[NA * H1];
    #pragma unroll
    for (int c = 0; c < NA * H1; ++c) { accA[c] = 0.f; accB[c] = 0.f; }

    const bool act = (tid < 250);
    const float4* e4A = nullptr;
    const float4* e4B = nullptr;
    float4 a0, a1, b0, b1;
    a0 = a1 = b0 = b1 = make_float4(0.f, 0.f, 0.f, 0.f);
    if (act) {
        e4A = (const float4*)(Wemb + (long)doc[tid] * DD);
        e4B = (const float4*)(Wemb + (long)doc[tid + 250] * DD);
        a0 = e4A[0]; a1 = e4A[1];
        b0 = e4B[0]; b1 = e4B[1];
    }

    const int db0s[5] = {0, 19, 38, 57, 75};
    #pragma unroll
    for (int p = 0; p < 4; ++p) {
        const int db0 = db0s[p], db1 = db0s[p + 1];
        const int nf4 = (db1 - db0) * 10;

        __syncthreads();
        for (int i = tid; i < NA * 190; i += 256) {
            const int a_ = i / 190, j = i - a_ * 190;
            if (j < nf4) {
                ((float4*)(apS + a_ * 760))[j] =
                    ((const float4*)(AP + a_ * (DD * H1) + db0 * 40))[j];
            }
        }
        __syncthreads();

        if (act) {
            for (int db = db0; db < db1; ++db) {
                float4 a2 = a1, b2 = b1;
                if (db < 73) { a2 = e4A[db + 2]; b2 = e4B[db + 2]; }
                const float av0 = a0.x, av1 = a0.y, av2 = a0.z, av3 = a0.w;
                const float bv0 = b0.x, bv1 = b0.y, bv2 = b0.z, bv3 = b0.w;
                const int o = (db - db0) * 40;
                #pragma unroll
                for (int a_ = 0; a_ < NA; ++a_) {
                    const float4* wp4 = (const float4*)(apS + a_ * 760 + o);
                    float w[40];
                    #pragma unroll
                    for (int j = 0; j < 10; ++j)
                        *reinterpret_cast<float4*>(&w[4 * j]) = wp4[j];
                    #pragma unroll
                    for (int h = 0; h < H1; ++h) {
                        const float w0 = w[h], w1 = w[10 + h],
                                    w2 = w[20 + h], w3 = w[30 + h];
                        accA[a_ * H1 + h] += av0 * w0 + av1 * w1 + av2 * w2 + av3 * w3;
                        accB[a_ * H1 + h] += bv0 * w0 + bv1 * w1 + bv2 * w2 + bv3 * w3;
                    }
                }
                a0 = a1; a1 = a2;
                b0 = b1; b1 = b2;
            }
        }
    }

    #pragma unroll
    for (int a_ = 0; a_ < NA; ++a_) {
        __syncthreads();
        if (act) {
            #pragma unroll
            for (int h = 0; h < H1; ++h) {
                adoc[tid][h]       = accA[a_ * H1 + h];
                adoc[tid + 250][h] = accB[a_ * H1 + h];
            }
        }
        __syncthreads();

        for (int l = tid; l < LL; l += 256) {
            const float* aerow = AE + a_ * 30;
            float s = 0.f;
            if (l > 0) {
                const float* ad = &adoc[l - 1][0];
                #pragma unroll
                for (int h = 0; h < H1; ++h) s += ad[h] * aerow[h];
            }
            {
                const float* ad = &adoc[l][0];
                #pragma unroll
                for (int h = 0; h < H1; ++h) s += ad[h] * aerow[H1 + h];
            }
            if (l < LL - 1) {
                const float* ad = &adoc[l + 1][0];
                #pragma unroll
                for (int h = 0; h < H1; ++h) s += ad[h] * aerow[2 * H1 + h];
            }
            lg[l] = s;
        }
        __syncthreads();

        if (tid < 64) {
            const int lane = tid;
            float mx = -1e30f;
            for (int p = lane; p < LL; p += 64) mx = fmaxf(mx, lg[p]);
            #pragma unroll
            for (int o = 32; o; o >>= 1) mx = fmaxf(mx, __shfl_xor(mx, o, 64));
            float sum = 0.f;
            for (int p = lane; p < LL; p += 64) {
                float pr = expf(lg[p] - mx);
                lg[p] = pr;
                sum += pr;
            }
            #pragma unroll
            for (int o = 32; o; o >>= 1) sum += __shfl_xor(sum, o, 64);
            float r[H1];
            #pragma unroll
            for (int h = 0; h < H1; ++h) r[h] = 0.f;
            for (int p = lane; p < LL; p += 64) {
                const float pr = lg[p];
                const float* ad = &adoc[p][0];
                #pragma unroll
                for (int h = 0; h < H1; ++h) r[h] += pr * ad[h];
            }
            #pragma unroll
            for (int h = 0; h < H1; ++h) {
                #pragma unroll
                for (int o = 32; o; o >>= 1) r[h] += __shfl_xor(r[h], o, 64);
            }
            if (lane == 0) {
                const float inv = 1.f / sum;
                float* out = Rep + (((long)side * NB + b) * NA + a_) * H1;
                #pragma unroll
                for (int h = 0; h < H1; ++h) out[h] = r[h] * inv;
            }
        }
    }
}

__global__ __launch_bounds__(64)
void k_final(const float* __restrict__ Rep, const int* __restrict__ Uids,
             const int* __restrict__ Iids, const float* __restrict__ M,
             const float* __restrict__ Uproj, const float* __restrict__ Uw,
             const float* __restrict__ Iproj, const float* __restrict__ Iw,
             const float* __restrict__ Bu, const float* __restrict__ Bi,
             const float* __restrict__ Bg, float* __restrict__ out)
{
    __shared__ float Ud[50], Idd[50], tmp[50], aff[25];
    const int b = blockIdx.x, lane = threadIdx.x;
    if (lane < 50) {
        Ud[lane]  = Rep[(long)b * 50 + lane];
        Idd[lane] = Rep[(long)NB * 50 + (long)b * 50 + lane];
    }
    __syncthreads();
    if (lane < 50) {
        const int c = lane / 10, h = lane % 10;
        float t = 0.f;
        #pragma unroll
        for (int k = 0; k < 10; ++k) t += M[h * 10 + k] * Idd[c * 10 + k];
        tmp[lane] = t;
    }
    __syncthreads();
    if (lane < 25) {
        const int a_ = lane / 5, c = lane % 5;
        float s = 0.f;
        #pragma unroll
        for (int h = 0; h < 10; ++h) s += Ud[a_ * 10 + h] * tmp[c * 10 + h];
        aff[lane] = fmaxf(s, 0.f);
    }
    __syncthreads();

    float hu1[5], hi1[5], tu[5], ti[5];
    if (lane < 50) {
        #pragma unroll
        for (int a_ = 0; a_ < 5; ++a_) {
            float su = 0.f, si = 0.f;
            #pragma unroll
            for (int h = 0; h < 10; ++h) {
                su += Uproj[lane * 10 + h] * Ud[a_ * 10 + h];
                si += Iproj[lane * 10 + h] * Idd[a_ * 10 + h];
            }
            hu1[a_] = su; hi1[a_] = si;
        }
    } else {
        #pragma unroll
        for (int a_ = 0; a_ < 5; ++a_) { hu1[a_] = 0.f; hi1[a_] = 0.f; }
    }
    const float uw = (lane < 50) ? Uw[lane] : 0.f;
    const float iw = (lane < 50) ? Iw[lane] : 0.f;
    #pragma unroll
    for (int a_ = 0; a_ < 5; ++a_) {
        float hu = hu1[a_], hi = hi1[a_];
        #pragma unroll
        for (int c = 0; c < 5; ++c) {
            hu += hi1[c] * aff[a_ * 5 + c];
            hi += hu1[c] * aff[c * 5 + a_];
        }
        tu[a_] = uw * fmaxf(hu, 0.f);
        ti[a_] = iw * fmaxf(hi, 0.f);
    }
    #pragma unroll
    for (int a_ = 0; a_ < 5; ++a_) {
        #pragma unroll
        for (int o = 32; o; o >>= 1) {
            tu[a_] += __shfl_xor(tu[a_], o, 64);
            ti[a_] += __shfl_xor(ti[a_], o, 64);
        }
    }
    if (lane == 0) {
        float mu = tu[0], mi = ti[0];
        #pragma unroll
        for (int a_ = 1; a_ < 5; ++a_) { mu = fmaxf(mu, tu[a_]); mi = fmaxf(mi, ti[a_]); }
        float eu[5], ei[5], su = 0.f, si = 0.f;
        #pragma unroll
        for (int a_ = 0; a_ < 5; ++a_) {
            eu[a_] = expf(tu[a_] - mu); su += eu[a_];
            ei[a_] = expf(ti[a_] - mi); si += ei[a_];
        }
        float R = 0.f;
        #pragma unroll
        for (int a_ = 0; a_ < 5; ++a_) {
            float ar = 0.f;
            #pragma unroll
            for (int h = 0; h < 10; ++h) ar += Ud[a_ * 10 + h] * Idd[a_ * 10 + h];
            R += (eu[a_] / su) * (ei[a_] / si) * ar;
        }
        R += Bu[Uids[b]] + Bi[Iids[b]] + Bg[0];
        out[b] = R;
    }
}

extern "C" void kernel_launch(void* const* d_in, const int* in_sizes, int n_in,
                              void* d_out, int out_size, void* d_ws, size_t ws_size,
                              hipStream_t stream)
{
    const int*   Uids  = (const int*)d_in[0];
    const int*   Iids  = (const int*)d_in[1];
    const int*   Udocs = (const int*)d_in[2];
    const int*   Idocs = (const int*)d_in[3];
    const float* Wemb  = (const float*)d_in[4];
    const float* AE    = (const float*)d_in[5];
    const float* AP    = (const float*)d_in[6];
    const float* M     = (const float*)d_in[7];
    const float* Uproj = (const float*)d_in[8];
    const float* Uw    = (const float*)d_in[9];
    const float* Iproj = (const float*)d_in[10];
    const float* Iw    = (const float*)d_in[11];
    const float* Bu    = (const float*)d_in[12];
    const float* Bi    = (const float*)d_in[13];
    const float* Bg    = (const float*)d_in[14];

    float* Rep = (float*)d_ws;                       // 102400 B
    float* out = (float*)d_out;
    const size_t REP_BYTES  = (size_t)2 * NB * NA * H1 * 4;
    const size_t PROJ_BYTES = (size_t)VV * PSTR * 4; // 11.2 MB

    if (ws_size >= REP_BYTES + PROJ_BYTES) {
        float* projT = (float*)((char*)d_ws + REP_BYTES);
        k_vproj<<<(VV + 63) / 64, 640, 15200, stream>>>(Wemb, AP, projT);
        k_attn2<<<2 * NB, 256, 0, stream>>>(Uids, Iids, Udocs, Idocs, projT, AE, Rep);
    } else {
        const size_t smem = 15200 + 22000 + 2000;
        k_aspect<<<2 * NB, 256, smem, stream>>>(Uids, Iids, Udocs, Idocs, Wemb, AE, AP, Rep);
    }
    k_final<<<NB, 64, 0, stream>>>(Rep, Uids, Iids, M, Uproj, Uw, Iproj, Iw, Bu, Bi, Bg, out);
}

// Round 33
// 83.207 us; speedup vs baseline: 1.3555x; 1.3555x over previous
//
#include <hip/hip_runtime.h>

#define NA 5
#define LL 500
#define DD 300
#define H1 10
#define H2 50
#define NB 256
#define VV 50000
#define PSTR 56   // projT row stride (floats): 16B-aligned rows
#define ADS 11    // adoc LDS row stride (odd -> conflict-free)

// r33: REVERT to r29 (83.6us, session best) verbatim. r30 (4-deep
// prefetch, null), r31 (2 rows/lane, -20%), r32 (10 waves + remap, -42%)
// all failed to beat r29's k_vproj; per r32's pre-commitment the
// wave-scaling direction is exhausted. k_vproj: aspect-per-wave (320-thr
// blocks, wa = tid>>6, lane = vocab row), exec-guarded literal LDS bases
// (keeps w[40] SROA-registers, VGPR 32, no spill), 4-pass AP staging.

__global__ __launch_bounds__(320, 1)
void k_vproj(const float* __restrict__ Wemb,
             const float* __restrict__ AP,   // [A][D][H1]
             float* __restrict__ projT)      // [VV][PSTR]
{
    extern __shared__ char smem[];
    float* apS = (float*)smem;               // 3800 f = 15200 B

    const int tid  = threadIdx.x;
    const int wa   = tid >> 6;               // wave index = aspect (uniform/wave)
    const int lane = tid & 63;
    const int v    = blockIdx.x * 64 + lane;
    const bool actV = (v < VV);
    const int vc = actV ? v : (VV - 1);      // clamp: compute, don't store

    float acc[H1];
    #pragma unroll
    for (int h = 0; h < H1; ++h) acc[h] = 0.f;

    const float4* e4 = (const float4*)(Wemb + (long)vc * DD);
    float4 a0 = e4[0], a1 = e4[1];

    const int db0s[5] = {0, 19, 38, 57, 75};
    #pragma unroll
    for (int p = 0; p < 4; ++p) {
        const int db0 = db0s[p], db1 = db0s[p + 1];
        const int nf4 = (db1 - db0) * 10;

        __syncthreads();
        for (int i = tid; i < NA * 190; i += 320) {   // stage slice (all aspects)
            const int a_ = i / 190, j = i - a_ * 190;
            if (j < nf4) {
                ((float4*)(apS + a_ * 760))[j] =
                    ((const float4*)(AP + a_ * (DD * H1) + db0 * 40))[j];
            }
        }
        __syncthreads();

        for (int db = db0; db < db1; ++db) {
            float4 a2 = a1;
            if (db < 73) a2 = e4[db + 2];             // 2-deep prefetch
            const float av0 = a0.x, av1 = a0.y, av2 = a0.z, av3 = a0.w;
            const int o = (db - db0) * 40;
            #pragma unroll
            for (int a_ = 0; a_ < NA; ++a_) {
                if (a_ == wa) {   // wave-uniform guard -> exec-skip, literal base
                    const float4* wp4 = (const float4*)(apS + a_ * 760 + o);
                    float w[40];
                    #pragma unroll
                    for (int j = 0; j < 10; ++j)
                        *reinterpret_cast<float4*>(&w[4 * j]) = wp4[j];
                    #pragma unroll
                    for (int h = 0; h < H1; ++h) {
                        const float w0 = w[h], w1 = w[10 + h],
                                    w2 = w[20 + h], w3 = w[30 + h];
                        acc[h] += av0 * w0 + av1 * w1 + av2 * w2 + av3 * w3;
                    }
                }
            }
            a0 = a1; a1 = a2;
        }
    }

    if (actV) {
        float* o = projT + (long)v * PSTR + wa * H1;  // 40B offsets -> 8B aligned
        #pragma unroll
        for (int j = 0; j < 5; ++j)
            *reinterpret_cast<float2*>(o + 2 * j) =
                *reinterpret_cast<float2*>(&acc[2 * j]);
    }
}

__global__ __launch_bounds__(256, 1)
void k_attn2(const int* __restrict__ Uids, const int* __restrict__ Iids,
             const int* __restrict__ Udocs, const int* __restrict__ Idocs,
             const float* __restrict__ projT,
             const float* __restrict__ AE,   // [A][30]
             float* __restrict__ Rep)        // [2][B][A][H1]
{
    __shared__ float adoc[LL][ADS];
    __shared__ float lg[LL];

    const int tid  = threadIdx.x;
    const int bid  = blockIdx.x;
    const int side = bid >> 8;
    const int b    = bid & 255;

    const int* ids  = side ? Iids : Uids;
    const int* docs = side ? Idocs : Udocs;
    const int uid = ids[b];
    const int* doc = docs + (long)uid * LL;

    const bool act = (tid < 250);
    float accA[NA * H1], accB[NA * H1];
    if (act) {
        const float* pA = projT + (long)doc[tid] * PSTR;
        const float* pB = projT + (long)doc[tid + 250] * PSTR;
        #pragma unroll
        for (int j = 0; j < 12; ++j) {
            *reinterpret_cast<float4*>(&accA[4 * j]) = ((const float4*)pA)[j];
            *reinterpret_cast<float4*>(&accB[4 * j]) = ((const float4*)pB)[j];
        }
        accA[48] = pA[48]; accA[49] = pA[49];
        accB[48] = pB[48]; accB[49] = pB[49];
    }

    // ---- phase 2: one aspect at a time through LDS (r16 verbatim) ----
    #pragma unroll
    for (int a_ = 0; a_ < NA; ++a_) {
        __syncthreads();
        if (act) {
            #pragma unroll
            for (int h = 0; h < H1; ++h) {
                adoc[tid][h]       = accA[a_ * H1 + h];
                adoc[tid + 250][h] = accB[a_ * H1 + h];
            }
        }
        __syncthreads();

        for (int l = tid; l < LL; l += 256) {
            const float* aerow = AE + a_ * 30;
            float s = 0.f;
            if (l > 0) {
                const float* ad = &adoc[l - 1][0];
                #pragma unroll
                for (int h = 0; h < H1; ++h) s += ad[h] * aerow[h];
            }
            {
                const float* ad = &adoc[l][0];
                #pragma unroll
                for (int h = 0; h < H1; ++h) s += ad[h] * aerow[H1 + h];
            }
            if (l < LL - 1) {
                const float* ad = &adoc[l + 1][0];
                #pragma unroll
                for (int h = 0; h < H1; ++h) s += ad[h] * aerow[2 * H1 + h];
            }
            lg[l] = s;
        }
        __syncthreads();

        if (tid < 64) {
            const int lane = tid;
            float mx = -1e30f;
            for (int p = lane; p < LL; p += 64) mx = fmaxf(mx, lg[p]);
            #pragma unroll
            for (int o = 32; o; o >>= 1) mx = fmaxf(mx, __shfl_xor(mx, o, 64));
            float sum = 0.f;
            for (int p = lane; p < LL; p += 64) {
                float pr = expf(lg[p] - mx);
                lg[p] = pr;
                sum += pr;
            }
            #pragma unroll
            for (int o = 32; o; o >>= 1) sum += __shfl_xor(sum, o, 64);
            float r[H1];
            #pragma unroll
            for (int h = 0; h < H1; ++h) r[h] = 0.f;
            for (int p = lane; p < LL; p += 64) {
                const float pr = lg[p];
                const float* ad = &adoc[p][0];
                #pragma unroll
                for (int h = 0; h < H1; ++h) r[h] += pr * ad[h];
            }
            #pragma unroll
            for (int h = 0; h < H1; ++h) {
                #pragma unroll
                for (int o = 32; o; o >>= 1) r[h] += __shfl_xor(r[h], o, 64);
            }
            if (lane == 0) {
                const float inv = 1.f / sum;
                float* out = Rep + (((long)side * NB + b) * NA + a_) * H1;
                #pragma unroll
                for (int h = 0; h < H1; ++h) out[h] = r[h] * inv;
            }
        }
    }
}

// ---------------- fallback fused path (r20, 158 us) ----------------
__global__ __launch_bounds__(256, 1)
void k_aspect(const int* __restrict__ Uids, const int* __restrict__ Iids,
              const int* __restrict__ Udocs, const int* __restrict__ Idocs,
              const float* __restrict__ Wemb,
              const float* __restrict__ AE,
              const float* __restrict__ AP,
              float* __restrict__ Rep)
{
    extern __shared__ char smem[];
    float* apS = (float*)smem;
    float (*adoc)[ADS] = (float(*)[ADS])(smem + 15200);
    float* lg = (float*)(smem + 15200 + 22000);

    const int tid  = threadIdx.x;
    const int bid  = blockIdx.x;
    const int side = bid >> 8;
    const int b    = bid & 255;

    const int* ids  = side ? Iids : Uids;
    const int* docs = side ? Idocs : Udocs;
    const int uid = ids[b];
    const int* doc = docs + (long)uid * LL;

    float accA[NA * H1], accB[NA * H1];
    #pragma unroll
    for (int c = 0; c < NA * H1; ++c) { accA[c] = 0.f; accB[c] = 0.f; }

    const bool act = (tid < 250);
    const float4* e4A = nullptr;
    const float4* e4B = nullptr;
    float4 a0, a1, b0, b1;
    a0 = a1 = b0 = b1 = make_float4(0.f, 0.f, 0.f, 0.f);
    if (act) {
        e4A = (const float4*)(Wemb + (long)doc[tid] * DD);
        e4B = (const float4*)(Wemb + (long)doc[tid + 250] * DD);
        a0 = e4A[0]; a1 = e4A[1];
        b0 = e4B[0]; b1 = e4B[1];
    }

    const int db0s[5] = {0, 19, 38, 57, 75};
    #pragma unroll
    for (int p = 0; p < 4; ++p) {
        const int db0 = db0s[p], db1 = db0s[p + 1];
        const int nf4 = (db1 - db0) * 10;

        __syncthreads();
        for (int i = tid; i < NA * 190; i += 256) {
            const int a_ = i / 190, j = i - a_ * 190;
            if (j < nf4) {
                ((float4*)(apS + a_ * 760))[j] =
                    ((const float4*)(AP + a_ * (DD * H1) + db0 * 40))[j];
            }
        }
        __syncthreads();

        if (act) {
            for (int db = db0; db < db1; ++db) {
                float4 a2 = a1, b2 = b1;
                if (db < 73) { a2 = e4A[db + 2]; b2 = e4B[db + 2]; }
                const float av0 = a0.x, av1 = a0.y, av2 = a0.z, av3 = a0.w;
                const float bv0 = b0.x, bv1 = b0.y, bv2 = b0.z, bv3 = b0.w;
                const int o = (db - db0) * 40;
                #pragma unroll
                for (int a_ = 0; a_ < NA; ++a_) {
                    const float4* wp4 = (const float4*)(apS + a_ * 760 + o);
                    float w[40];
                    #pragma unroll
                    for (int j = 0; j < 10; ++j)
                        *reinterpret_cast<float4*>(&w[4 * j]) = wp4[j];
                    #pragma unroll
                    for (int h = 0; h < H1; ++h) {
                        const float w0 = w[h], w1 = w[10 + h],
                                    w2 = w[20 + h], w3 = w[30 + h];
                        accA[a_ * H1 + h] += av0 * w0 + av1 * w1 + av2 * w2 + av3 * w3;
                        accB[a_ * H1 + h] += bv0 * w0 + bv1 * w1 + bv2 * w2 + bv3 * w3;
                    }
                }
                a0 = a1; a1 = a2;
                b0 = b1; b1 = b2;
            }
        }
    }

    #pragma unroll
    for (int a_ = 0; a_ < NA; ++a_) {
        __syncthreads();
        if (act) {
            #pragma unroll
            for (int h = 0; h < H1; ++h) {
                adoc[tid][h]       = accA[a_ * H1 + h];
                adoc[tid + 250][h] = accB[a_ * H1 + h];
            }
        }
        __syncthreads();

        for (int l = tid; l < LL; l += 256) {
            const float* aerow = AE + a_ * 30;
            float s = 0.f;
            if (l > 0) {
                const float* ad = &adoc[l - 1][0];
                #pragma unroll
                for (int h = 0; h < H1; ++h) s += ad[h] * aerow[h];
            }
            {
                const float* ad = &adoc[l][0];
                #pragma unroll
                for (int h = 0; h < H1; ++h) s += ad[h] * aerow[H1 + h];
            }
            if (l < LL - 1) {
                const float* ad = &adoc[l + 1][0];
                #pragma unroll
                for (int h = 0; h < H1; ++h) s += ad[h] * aerow[2 * H1 + h];
            }
            lg[l] = s;
        }
        __syncthreads();

        if (tid < 64) {
            const int lane = tid;
            float mx = -1e30f;
            for (int p = lane; p < LL; p += 64) mx = fmaxf(mx, lg[p]);
            #pragma unroll
            for (int o = 32; o; o >>= 1) mx = fmaxf(mx, __shfl_xor(mx, o, 64));
            float sum = 0.f;
            for (int p = lane; p < LL; p += 64) {
                float pr = expf(lg[p] - mx);
                lg[p] = pr;
                sum += pr;
            }
            #pragma unroll
            for (int o = 32; o; o >>= 1) sum += __shfl_xor(sum, o, 64);
            float r[H1];
            #pragma unroll
            for (int h = 0; h < H1; ++h) r[h] = 0.f;
            for (int p = lane; p < LL; p += 64) {
                const float pr = lg[p];
                const float* ad = &adoc[p][0];
                #pragma unroll
                for (int h = 0; h < H1; ++h) r[h] += pr * ad[h];
            }
            #pragma unroll
            for (int h = 0; h < H1; ++h) {
                #pragma unroll
                for (int o = 32; o; o >>= 1) r[h] += __shfl_xor(r[h], o, 64);
            }
            if (lane == 0) {
                const float inv = 1.f / sum;
                float* out = Rep + (((long)side * NB + b) * NA + a_) * H1;
                #pragma unroll
                for (int h = 0; h < H1; ++h) out[h] = r[h] * inv;
            }
        }
    }
}

__global__ __launch_bounds__(64)
void k_final(const float* __restrict__ Rep, const int* __restrict__ Uids,
             const int* __restrict__ Iids, const float* __restrict__ M,
             const float* __restrict__ Uproj, const float* __restrict__ Uw,
             const float* __restrict__ Iproj, const float* __restrict__ Iw,
             const float* __restrict__ Bu, const float* __restrict__ Bi,
             const float* __restrict__ Bg, float* __restrict__ out)
{
    __shared__ float Ud[50], Idd[50], tmp[50], aff[25];
    const int b = blockIdx.x, lane = threadIdx.x;
    if (lane < 50) {
        Ud[lane]  = Rep[(long)b * 50 + lane];
        Idd[lane] = Rep[(long)NB * 50 + (long)b * 50 + lane];
    }
    __syncthreads();
    if (lane < 50) {
        const int c = lane / 10, h = lane % 10;
        float t = 0.f;
        #pragma unroll
        for (int k = 0; k < 10; ++k) t += M[h * 10 + k] * Idd[c * 10 + k];
        tmp[lane] = t;
    }
    __syncthreads();
    if (lane < 25) {
        const int a_ = lane / 5, c = lane % 5;
        float s = 0.f;
        #pragma unroll
        for (int h = 0; h < 10; ++h) s += Ud[a_ * 10 + h] * tmp[c * 10 + h];
        aff[lane] = fmaxf(s, 0.f);
    }
    __syncthreads();

    float hu1[5], hi1[5], tu[5], ti[5];
    if (lane < 50) {
        #pragma unroll
        for (int a_ = 0; a_ < 5; ++a_) {
            float su = 0.f, si = 0.f;
            #pragma unroll
            for (int h = 0; h < 10; ++h) {
                su += Uproj[lane * 10 + h] * Ud[a_ * 10 + h];
                si += Iproj[lane * 10 + h] * Idd[a_ * 10 + h];
            }
            hu1[a_] = su; hi1[a_] = si;
        }
    } else {
        #pragma unroll
        for (int a_ = 0; a_ < 5; ++a_) { hu1[a_] = 0.f; hi1[a_] = 0.f; }
    }
    const float uw = (lane < 50) ? Uw[lane] : 0.f;
    const float iw = (lane < 50) ? Iw[lane] : 0.f;
    #pragma unroll
    for (int a_ = 0; a_ < 5; ++a_) {
        float hu = hu1[a_], hi = hi1[a_];
        #pragma unroll
        for (int c = 0; c < 5; ++c) {
            hu += hi1[c] * aff[a_ * 5 + c];
            hi += hu1[c] * aff[c * 5 + a_];
        }
        tu[a_] = uw * fmaxf(hu, 0.f);
        ti[a_] = iw * fmaxf(hi, 0.f);
    }
    #pragma unroll
    for (int a_ = 0; a_ < 5; ++a_) {
        #pragma unroll
        for (int o = 32; o; o >>= 1) {
            tu[a_] += __shfl_xor(tu[a_], o, 64);
            ti[a_] += __shfl_xor(ti[a_], o, 64);
        }
    }
    if (lane == 0) {
        float mu = tu[0], mi = ti[0];
        #pragma unroll
        for (int a_ = 1; a_ < 5; ++a_) { mu = fmaxf(mu, tu[a_]); mi = fmaxf(mi, ti[a_]); }
        float eu[5], ei[5], su = 0.f, si = 0.f;
        #pragma unroll
        for (int a_ = 0; a_ < 5; ++a_) {
            eu[a_] = expf(tu[a_] - mu); su += eu[a_];
            ei[a_] = expf(ti[a_] - mi); si += ei[a_];
        }
        float R = 0.f;
        #pragma unroll
        for (int a_ = 0; a_ < 5; ++a_) {
            float ar = 0.f;
            #pragma unroll
            for (int h = 0; h < 10; ++h) ar += Ud[a_ * 10 + h] * Idd[a_ * 10 + h];
            R += (eu[a_] / su) * (ei[a_] / si) * ar;
        }
        R += Bu[Uids[b]] + Bi[Iids[b]] + Bg[0];
        out[b] = R;
    }
}

extern "C" void kernel_launch(void* const* d_in, const int* in_sizes, int n_in,
                              void* d_out, int out_size, void* d_ws, size_t ws_size,
                              hipStream_t stream)
{
    const int*   Uids  = (const int*)d_in[0];
    const int*   Iids  = (const int*)d_in[1];
    const int*   Udocs = (const int*)d_in[2];
    const int*   Idocs = (const int*)d_in[3];
    const float* Wemb  = (const float*)d_in[4];
    const float* AE    = (const float*)d_in[5];
    const float* AP    = (const float*)d_in[6];
    const float* M     = (const float*)d_in[7];
    const float* Uproj = (const float*)d_in[8];
    const float* Uw    = (const float*)d_in[9];
    const float* Iproj = (const float*)d_in[10];
    const float* Iw    = (const float*)d_in[11];
    const float* Bu    = (const float*)d_in[12];
    const float* Bi    = (const float*)d_in[13];
    const float* Bg    = (const float*)d_in[14];

    float* Rep = (float*)d_ws;                       // 102400 B
    float* out = (float*)d_out;
    const size_t REP_BYTES  = (size_t)2 * NB * NA * H1 * 4;
    const size_t PROJ_BYTES = (size_t)VV * PSTR * 4; // 11.2 MB

    if (ws_size >= REP_BYTES + PROJ_BYTES) {
        float* projT = (float*)((char*)d_ws + REP_BYTES);
        k_vproj<<<(VV + 63) / 64, 320, 15200, stream>>>(Wemb, AP, projT);
        k_attn2<<<2 * NB, 256, 0, stream>>>(Uids, Iids, Udocs, Idocs, projT, AE, Rep);
    } else {
        const size_t smem = 15200 + 22000 + 2000;
        k_aspect<<<2 * NB, 256, smem, stream>>>(Uids, Iids, Udocs, Idocs, Wemb, AE, AP, Rep);
    }
    k_final<<<NB, 64, 0, stream>>>(Rep, Uids, Iids, M, Uproj, Uw, Iproj, Iw, Bu, Bi, Bg, out);
}